// Round 1
// baseline (607.663 us; speedup 1.0000x reference)
//
#include <hip/hip_runtime.h>
#include <stdint.h>

#define B_ 4
#define T_ 2048
#define C_ 1024
#define H_ 16
#define HD 64

typedef __attribute__((ext_vector_type(8))) short bf16x8;
typedef __attribute__((ext_vector_type(4))) float v4f;

static __device__ __forceinline__ short f2bf(float f) {
    union { float f; uint32_t u; } v; v.f = f;
    uint32_t u = v.u;
    uint32_t r = (u + 0x7fffu + ((u >> 16) & 1u)) >> 16;
    return (short)(r & 0xffffu);
}

// C[m,n] = sum_k A[m,k] * W[n,k]   (nn.Linear NT gemm), bf16 MFMA 16x16x32.
// MODE 0: A fp32, out bf16 scattered to (b,h,t,d)
// MODE 1: A fp32, out bf16 scattered to (b,h,d,t)  (V transposed for PV)
// MODE 2: A bf16, out fp32 row-major + bias
template <int MODE>
__global__ __launch_bounds__(256) void gemm_nt(
    const void* __restrict__ Av, const float* __restrict__ Wf,
    void* __restrict__ Out, const float* __restrict__ bias, int M, int K)
{
    __shared__ short As[64 * 40];   // 64 rows x 32 k, pad to 40 (2-way bank alias = free)
    __shared__ short Bs[64 * 40];
    const int t = threadIdx.x;
    const int w = t >> 6, l = t & 63, g = l >> 4, c = l & 15;
    const int m0 = blockIdx.x * 64, n0 = blockIdx.y * 64;
    const int row = t >> 2, chunk = t & 3;

    v4f acc[4];
    for (int j = 0; j < 4; ++j) acc[j] = (v4f){0.f, 0.f, 0.f, 0.f};

    for (int k0 = 0; k0 < K; k0 += 32) {
        // stage A tile
        if (MODE == 2) {
            const short* Ab = (const short*)Av;
            *(bf16x8*)&As[row * 40 + chunk * 8] =
                *(const bf16x8*)&Ab[(size_t)(m0 + row) * K + k0 + chunk * 8];
        } else {
            const float* Af = (const float*)Av;
            const float* p = &Af[(size_t)(m0 + row) * K + k0 + chunk * 8];
            v4f a0 = *(const v4f*)p, a1 = *(const v4f*)(p + 4);
            bf16x8 sv;
            sv[0] = f2bf(a0[0]); sv[1] = f2bf(a0[1]); sv[2] = f2bf(a0[2]); sv[3] = f2bf(a0[3]);
            sv[4] = f2bf(a1[0]); sv[5] = f2bf(a1[1]); sv[6] = f2bf(a1[2]); sv[7] = f2bf(a1[3]);
            *(bf16x8*)&As[row * 40 + chunk * 8] = sv;
        }
        // stage B tile (W fp32, rows are output features n)
        {
            const float* p = &Wf[(size_t)(n0 + row) * K + k0 + chunk * 8];
            v4f b0 = *(const v4f*)p, b1 = *(const v4f*)(p + 4);
            bf16x8 sv;
            sv[0] = f2bf(b0[0]); sv[1] = f2bf(b0[1]); sv[2] = f2bf(b0[2]); sv[3] = f2bf(b0[3]);
            sv[4] = f2bf(b1[0]); sv[5] = f2bf(b1[1]); sv[6] = f2bf(b1[2]); sv[7] = f2bf(b1[3]);
            *(bf16x8*)&Bs[row * 40 + chunk * 8] = sv;
        }
        __syncthreads();
        // A frag: A[m=c][k=g*8+j] ; B frag: W[n=c][k=g*8+j] (B-operand lane n + 16*quad)
        bf16x8 af = *(const bf16x8*)&As[(w * 16 + c) * 40 + g * 8];
        for (int j = 0; j < 4; ++j) {
            bf16x8 bf = *(const bf16x8*)&Bs[(j * 16 + c) * 40 + g * 8];
            acc[j] = __builtin_amdgcn_mfma_f32_16x16x32_bf16(af, bf, acc[j], 0, 0, 0);
        }
        __syncthreads();
    }
    // epilogue: C/D layout col = lane&15, row = (lane>>4)*4 + reg  [m89/m91]
    for (int j = 0; j < 4; ++j) {
        for (int r = 0; r < 4; ++r) {
            int m = m0 + w * 16 + g * 4 + r;
            int n = n0 + j * 16 + c;
            float vv = acc[j][r];
            if (MODE == 2) {
                ((float*)Out)[(size_t)m * C_ + n] = vv + bias[n];
            } else {
                int b = m >> 11, tt = m & (T_ - 1);
                int h = n >> 6, d = n & 63;
                short* o = (short*)Out;
                if (MODE == 0) o[((size_t)(b * H_ + h) * T_ + tt) * HD + d] = f2bf(vv);
                else           o[((size_t)(b * H_ + h) * HD + d) * T_ + tt] = f2bf(vv);
            }
        }
    }
}

// Flash attention, causal. Q,K: (B,H,T,64) bf16; Vt: (B,H,64,T) bf16; Y: (B,T,C) bf16.
// Block = (b, h, 64 q rows); 4 waves x 16 q rows; 64-key tiles.
__global__ __launch_bounds__(256) void attn_kernel(
    const short* __restrict__ Q, const short* __restrict__ Kp,
    const short* __restrict__ Vt, short* __restrict__ Y)
{
    __shared__ short Ks[64 * 72];        // [key][d] pad 72
    __shared__ short Vs[64 * 72];        // [d][key] pad 72
    __shared__ short Ps[4 * 16 * 72];    // per-wave P: [16 q][64 key] pad 72
    const int t = threadIdx.x;
    const int w = t >> 6, l = t & 63, g = l >> 4, c = l & 15;
    int bx = blockIdx.x;
    const int qt = bx & 31; bx >>= 5;
    const int h = bx & 15; const int b = bx >> 4;
    const int qbase = qt * 64;
    const size_t bh = (size_t)(b * H_ + h);

    // Q fragments held in registers for whole block: A[m=c][d-chunk]
    bf16x8 qf0, qf1;
    {
        const short* qp = &Q[(bh * T_ + qbase + w * 16 + c) * HD + g * 8];
        qf0 = *(const bf16x8*)qp;
        qf1 = *(const bf16x8*)(qp + 32);
    }

    float m2[4], lsum[4], alpha[4];
    v4f O[4];
    for (int r = 0; r < 4; ++r) { m2[r] = -3.0e38f; lsum[r] = 0.f; }
    for (int d = 0; d < 4; ++d) O[d] = (v4f){0.f, 0.f, 0.f, 0.f};

    const float sc = 0.18033688011112042f;  // log2(e) / sqrt(64)

    for (int kb = 0; kb <= qt; ++kb) {
        const int kbase = kb * 64;
        __syncthreads();
        for (int i = 0; i < 2; ++i) {
            int id = t + i * 256;           // 512 chunks of 16B per tile
            int rr = id >> 3, cc = id & 7;
            *(bf16x8*)&Ks[rr * 72 + cc * 8] =
                *(const bf16x8*)&Kp[(bh * T_ + kbase + rr) * HD + cc * 8];
            *(bf16x8*)&Vs[rr * 72 + cc * 8] =
                *(const bf16x8*)&Vt[(bh * HD + rr) * T_ + kbase + cc * 8];
        }
        __syncthreads();

        // S tiles: S[q][key], key tile j covers keys kbase+j*16..+16
        float s2[4][4];
        for (int j = 0; j < 4; ++j) {
            bf16x8 kf0 = *(const bf16x8*)&Ks[(j * 16 + c) * 72 + g * 8];
            bf16x8 kf1 = *(const bf16x8*)&Ks[(j * 16 + c) * 72 + 32 + g * 8];
            v4f sa = (v4f){0.f, 0.f, 0.f, 0.f};
            sa = __builtin_amdgcn_mfma_f32_16x16x32_bf16(qf0, kf0, sa, 0, 0, 0);
            sa = __builtin_amdgcn_mfma_f32_16x16x32_bf16(qf1, kf1, sa, 0, 0, 0);
            for (int r = 0; r < 4; ++r) s2[j][r] = sa[r] * sc;
        }
        if (kb == qt) {  // only the diagonal tile needs masking
            for (int j = 0; j < 4; ++j) {
                int key = kbase + j * 16 + c;
                for (int r = 0; r < 4; ++r) {
                    int q = qbase + w * 16 + g * 4 + r;
                    if (key > q) s2[j][r] = -3.0e38f;
                }
            }
        }
        // online softmax (rows live across the 16 lanes of each quad-group)
        for (int r = 0; r < 4; ++r) {
            float rm = fmaxf(fmaxf(s2[0][r], s2[1][r]), fmaxf(s2[2][r], s2[3][r]));
            rm = fmaxf(rm, __shfl_xor(rm, 1));
            rm = fmaxf(rm, __shfl_xor(rm, 2));
            rm = fmaxf(rm, __shfl_xor(rm, 4));
            rm = fmaxf(rm, __shfl_xor(rm, 8));
            float mn = fmaxf(m2[r], rm);
            alpha[r] = __builtin_amdgcn_exp2f(m2[r] - mn);
            m2[r] = mn;
        }
        for (int r = 0; r < 4; ++r) {
            float ps = 0.f;
            for (int j = 0; j < 4; ++j) {
                float p = __builtin_amdgcn_exp2f(s2[j][r] - m2[r]);
                ps += p;
                Ps[w * 1152 + (g * 4 + r) * 72 + j * 16 + c] = f2bf(p);
            }
            ps += __shfl_xor(ps, 1); ps += __shfl_xor(ps, 2);
            ps += __shfl_xor(ps, 4); ps += __shfl_xor(ps, 8);
            lsum[r] = lsum[r] * alpha[r] + ps;
            for (int d = 0; d < 4; ++d) O[d][r] *= alpha[r];
        }
        // PV: O[q][d] += P[q][key] * V[key][d]; P via LDS round-trip to A-layout
        for (int s = 0; s < 2; ++s) {
            bf16x8 af = *(const bf16x8*)&Ps[w * 1152 + c * 72 + s * 32 + g * 8];
            for (int d = 0; d < 4; ++d) {
                bf16x8 vf = *(const bf16x8*)&Vs[(d * 16 + c) * 72 + s * 32 + g * 8];
                O[d] = __builtin_amdgcn_mfma_f32_16x16x32_bf16(af, vf, O[d], 0, 0, 0);
            }
        }
    }
    // epilogue: Y is (B,T,H*64) row-major
    for (int r = 0; r < 4; ++r) {
        float rl = 1.0f / lsum[r];
        size_t rowoff = ((size_t)b * T_ + qbase + w * 16 + g * 4 + r) * C_ + h * HD;
        for (int d = 0; d < 4; ++d)
            Y[rowoff + d * 16 + c] = f2bf(O[d][r] * rl);
    }
}

extern "C" void kernel_launch(void* const* d_in, const int* in_sizes, int n_in,
                              void* d_out, int out_size, void* d_ws, size_t ws_size,
                              hipStream_t stream) {
    const float* xq = (const float*)d_in[0];
    const float* xk = (const float*)d_in[1];
    const float* xv = (const float*)d_in[2];
    const float* Wq = (const float*)d_in[3];
    const float* Wk = (const float*)d_in[4];
    const float* Wv = (const float*)d_in[5];
    const float* Wo = (const float*)d_in[6];
    const float* bo = (const float*)d_in[7];

    const size_t NE = (size_t)B_ * H_ * T_ * HD;  // 8.4M elems, 16MB bf16 each
    short* Qh = (short*)d_ws;
    short* Kh = Qh + NE;
    short* Vt = Kh + NE;
    short* Y  = Vt + NE;   // total 64MB of ws

    dim3 grid(128, 16), blk(256);
    hipLaunchKernelGGL((gemm_nt<0>), grid, blk, 0, stream, (const void*)xq, Wq, (void*)Qh, (const float*)nullptr, B_ * T_, C_);
    hipLaunchKernelGGL((gemm_nt<0>), grid, blk, 0, stream, (const void*)xk, Wk, (void*)Kh, (const float*)nullptr, B_ * T_, C_);
    hipLaunchKernelGGL((gemm_nt<1>), grid, blk, 0, stream, (const void*)xv, Wv, (void*)Vt, (const float*)nullptr, B_ * T_, C_);
    hipLaunchKernelGGL(attn_kernel, dim3(B_ * H_ * (T_ / 64)), blk, 0, stream, Qh, Kh, Vt, Y);
    hipLaunchKernelGGL((gemm_nt<2>), grid, blk, 0, stream, (const void*)Y, Wo, d_out, bo, B_ * T_, C_);
}

// Round 2
// 486.676 us; speedup vs baseline: 1.2486x; 1.2486x over previous
//
#include <hip/hip_runtime.h>
#include <stdint.h>

#define B_ 4
#define T_ 2048
#define C_ 1024
#define H_ 16
#define HD 64

typedef __attribute__((ext_vector_type(8))) short bf16x8;
typedef __attribute__((ext_vector_type(4))) float v4f;

static __device__ __forceinline__ short f2bf(float f) {
    union { float f; uint32_t u; } v; v.f = f;
    uint32_t u = v.u;
    uint32_t r = (u + 0x7fffu + ((u >> 16) & 1u)) >> 16;
    return (short)(r & 0xffffu);
}
static __device__ __forceinline__ short f2bf_trunc(float f) {
    union { float f; uint32_t u; } v; v.f = f;
    return (short)(v.u >> 16);
}
static __device__ __forceinline__ bf16x8 cvt8(v4f a0, v4f a1) {
    bf16x8 s;
    s[0] = f2bf(a0[0]); s[1] = f2bf(a0[1]); s[2] = f2bf(a0[2]); s[3] = f2bf(a0[3]);
    s[4] = f2bf(a1[0]); s[5] = f2bf(a1[1]); s[6] = f2bf(a1[2]); s[7] = f2bf(a1[3]);
    return s;
}

// C[m,n] = sum_k A[m,k] * W[n,k]  (nn.Linear NT), 128x128 tile, 4 waves 2x2,
// 4x4 16x16x32 bf16 MFMA per wave. LDS rows padded to 40 shorts (80B stride:
// reads 2-way bank alias = free, staging writes bank-balanced).
// MODE 0: A fp32, out bf16 -> (b,h,t,d) ; MODE 1: A fp32, out bf16 -> (b,h,d,t)
// MODE 2: A bf16, out fp32 row-major + bias
template <int MODE>
__global__ __launch_bounds__(256) void gemm_nt(
    const void* __restrict__ Av, const float* __restrict__ Wf,
    void* __restrict__ Out, const float* __restrict__ bias, int M, int K)
{
    __shared__ short As[128 * 40];
    __shared__ short Bs[128 * 40];
    const int t = threadIdx.x;
    const int w = t >> 6, l = t & 63, g = l >> 4, c = l & 15;
    const int wm = w & 1, wn = w >> 1;
    const int m0 = blockIdx.x * 128, n0 = blockIdx.y * 128;

    v4f acc[4][4];
#pragma unroll
    for (int i = 0; i < 4; ++i)
#pragma unroll
        for (int j = 0; j < 4; ++j) acc[i][j] = (v4f){0.f, 0.f, 0.f, 0.f};

    for (int k0 = 0; k0 < K; k0 += 32) {
#pragma unroll
        for (int i = 0; i < 2; ++i) {
            int id = i * 256 + t;              // 512 chunks of 8 elems (16B bf16)
            int row = id >> 2, sub = id & 3;
            if (MODE == 2) {
                const short* Ab = (const short*)Av;
                *(bf16x8*)&As[row * 40 + sub * 8] =
                    *(const bf16x8*)&Ab[(size_t)(m0 + row) * K + k0 + sub * 8];
            } else {
                const float* Af = (const float*)Av;
                const float* p = &Af[(size_t)(m0 + row) * K + k0 + sub * 8];
                *(bf16x8*)&As[row * 40 + sub * 8] = cvt8(*(const v4f*)p, *(const v4f*)(p + 4));
            }
            const float* q = &Wf[(size_t)(n0 + row) * K + k0 + sub * 8];
            *(bf16x8*)&Bs[row * 40 + sub * 8] = cvt8(*(const v4f*)q, *(const v4f*)(q + 4));
        }
        __syncthreads();
        bf16x8 af[4], bfr[4];
#pragma unroll
        for (int i = 0; i < 4; ++i)
            af[i] = *(const bf16x8*)&As[(wm * 64 + i * 16 + c) * 40 + g * 8];
#pragma unroll
        for (int j = 0; j < 4; ++j)
            bfr[j] = *(const bf16x8*)&Bs[(wn * 64 + j * 16 + c) * 40 + g * 8];
#pragma unroll
        for (int i = 0; i < 4; ++i)
#pragma unroll
            for (int j = 0; j < 4; ++j)
                acc[i][j] = __builtin_amdgcn_mfma_f32_16x16x32_bf16(af[i], bfr[j], acc[i][j], 0, 0, 0);
        __syncthreads();
    }
    // C/D layout: col = lane&15, row = (lane>>4)*4 + reg  [m89/m91]
#pragma unroll
    for (int i = 0; i < 4; ++i)
#pragma unroll
        for (int j = 0; j < 4; ++j)
#pragma unroll
            for (int r = 0; r < 4; ++r) {
                int m = m0 + wm * 64 + i * 16 + g * 4 + r;
                int n = n0 + wn * 64 + j * 16 + c;
                float vv = acc[i][j][r];
                if (MODE == 2) {
                    ((float*)Out)[(size_t)m * C_ + n] = vv + bias[n];
                } else {
                    int b = m >> 11, tt = m & (T_ - 1);
                    int h = n >> 6, d = n & 63;
                    short* o = (short*)Out;
                    if (MODE == 0) o[((size_t)(b * H_ + h) * T_ + tt) * HD + d] = f2bf(vv);
                    else           o[((size_t)(b * H_ + h) * HD + d) * T_ + tt] = f2bf(vv);
                }
            }
}

// Flash attention, causal. Q,K: (B,H,T,64) bf16; Vt: (B,H,64,T) bf16; Y: (B,T,C) bf16.
// Block = (b, h, q-tile pair {p, 31-p}) -> every block does exactly 33 k-tiles.
// Row-sum ell accumulated via MFMA against all-ones B fragment (no shuffles).
__global__ __launch_bounds__(256) void attn_kernel(
    const short* __restrict__ Q, const short* __restrict__ Kp,
    const short* __restrict__ Vt, short* __restrict__ Y)
{
    __shared__ short Ks[64 * 72];        // [key][d] pad 72
    __shared__ short Vs[64 * 72];        // [d][key] pad 72
    __shared__ short Ps[4 * 16 * 72];    // per-wave P: [16 q][64 key] pad 72
    const int t = threadIdx.x;
    const int w = t >> 6, l = t & 63, g = l >> 4, c = l & 15;
    const int p = blockIdx.x & 15;
    const size_t bh = blockIdx.x >> 4;

    bf16x8 ones;
#pragma unroll
    for (int i = 0; i < 8; ++i) ones[i] = (short)0x3F80;  // bf16 1.0

    const float sc = 0.18033688011112042f;  // log2(e) / sqrt(64)

    for (int qi = 0; qi < 2; ++qi) {
        const int qt = qi ? (31 - p) : p;
        const int qbase = qt * 64;

        bf16x8 qf0, qf1;
        {
            const short* qp = &Q[(bh * T_ + qbase + w * 16 + c) * HD + g * 8];
            qf0 = *(const bf16x8*)qp;
            qf1 = *(const bf16x8*)(qp + 32);
        }

        float m2[4], alpha[4];
        v4f O[4], accl;
#pragma unroll
        for (int r = 0; r < 4; ++r) m2[r] = -3.0e38f;
        accl = (v4f){0.f, 0.f, 0.f, 0.f};
#pragma unroll
        for (int d = 0; d < 4; ++d) O[d] = (v4f){0.f, 0.f, 0.f, 0.f};

        for (int kb = 0; kb <= qt; ++kb) {
            const int kbase = kb * 64;
            __syncthreads();
#pragma unroll
            for (int i = 0; i < 2; ++i) {
                int id = t + i * 256;           // 512 chunks of 16B per tile
                int rr = id >> 3, cc = id & 7;
                *(bf16x8*)&Ks[rr * 72 + cc * 8] =
                    *(const bf16x8*)&Kp[(bh * T_ + kbase + rr) * HD + cc * 8];
                *(bf16x8*)&Vs[rr * 72 + cc * 8] =
                    *(const bf16x8*)&Vt[(bh * HD + rr) * T_ + kbase + cc * 8];
            }
            __syncthreads();

            float s2[4][4];
#pragma unroll
            for (int j = 0; j < 4; ++j) {
                bf16x8 kf0 = *(const bf16x8*)&Ks[(j * 16 + c) * 72 + g * 8];
                bf16x8 kf1 = *(const bf16x8*)&Ks[(j * 16 + c) * 72 + 32 + g * 8];
                v4f sa = (v4f){0.f, 0.f, 0.f, 0.f};
                sa = __builtin_amdgcn_mfma_f32_16x16x32_bf16(qf0, kf0, sa, 0, 0, 0);
                sa = __builtin_amdgcn_mfma_f32_16x16x32_bf16(qf1, kf1, sa, 0, 0, 0);
#pragma unroll
                for (int r = 0; r < 4; ++r) s2[j][r] = sa[r] * sc;
            }
            if (kb == qt) {  // diagonal tile mask
#pragma unroll
                for (int j = 0; j < 4; ++j) {
                    int key = kbase + j * 16 + c;
#pragma unroll
                    for (int r = 0; r < 4; ++r) {
                        int q = qbase + w * 16 + g * 4 + r;
                        if (key > q) s2[j][r] = -3.0e38f;
                    }
                }
            }
#pragma unroll
            for (int r = 0; r < 4; ++r) {
                float rm = fmaxf(fmaxf(s2[0][r], s2[1][r]), fmaxf(s2[2][r], s2[3][r]));
                rm = fmaxf(rm, __shfl_xor(rm, 1));
                rm = fmaxf(rm, __shfl_xor(rm, 2));
                rm = fmaxf(rm, __shfl_xor(rm, 4));
                rm = fmaxf(rm, __shfl_xor(rm, 8));
                float mn = fmaxf(m2[r], rm);
                alpha[r] = __builtin_amdgcn_exp2f(m2[r] - mn);
                m2[r] = mn;
            }
#pragma unroll
            for (int r = 0; r < 4; ++r) {
#pragma unroll
                for (int j = 0; j < 4; ++j) {
                    float pp = __builtin_amdgcn_exp2f(s2[j][r] - m2[r]);
                    Ps[w * 1152 + (g * 4 + r) * 72 + j * 16 + c] = f2bf_trunc(pp);
                }
                accl[r] *= alpha[r];
#pragma unroll
                for (int d = 0; d < 4; ++d) O[d][r] *= alpha[r];
            }
            // PV + row-sum: A-frag via LDS round-trip; ell via ones-B MFMA
#pragma unroll
            for (int s = 0; s < 2; ++s) {
                bf16x8 af = *(const bf16x8*)&Ps[w * 1152 + c * 72 + s * 32 + g * 8];
#pragma unroll
                for (int d = 0; d < 4; ++d) {
                    bf16x8 vf = *(const bf16x8*)&Vs[(d * 16 + c) * 72 + s * 32 + g * 8];
                    O[d] = __builtin_amdgcn_mfma_f32_16x16x32_bf16(af, vf, O[d], 0, 0, 0);
                }
                accl = __builtin_amdgcn_mfma_f32_16x16x32_bf16(af, ones, accl, 0, 0, 0);
            }
        }
        // epilogue: every lane holds its own row's ell in accl[r] (all cols equal)
#pragma unroll
        for (int r = 0; r < 4; ++r) {
            float rl = 1.0f / accl[r];
            size_t rowoff = ((size_t)(bh >> 4) * T_ + qbase + w * 16 + g * 4 + r) * C_ + (bh & 15) * HD;
#pragma unroll
            for (int d = 0; d < 4; ++d)
                Y[rowoff + d * 16 + c] = f2bf(O[d][r] * rl);
        }
    }
}

extern "C" void kernel_launch(void* const* d_in, const int* in_sizes, int n_in,
                              void* d_out, int out_size, void* d_ws, size_t ws_size,
                              hipStream_t stream) {
    const float* xq = (const float*)d_in[0];
    const float* xk = (const float*)d_in[1];
    const float* xv = (const float*)d_in[2];
    const float* Wq = (const float*)d_in[3];
    const float* Wk = (const float*)d_in[4];
    const float* Wv = (const float*)d_in[5];
    const float* Wo = (const float*)d_in[6];
    const float* bo = (const float*)d_in[7];

    const size_t NE = (size_t)B_ * H_ * T_ * HD;  // 8.4M elems, 16MB bf16 each
    short* Qh = (short*)d_ws;
    short* Kh = Qh + NE;
    short* Vt = Kh + NE;
    short* Y  = Vt + NE;   // total 64MB of ws

    dim3 grid(64, 8), blk(256);
    hipLaunchKernelGGL((gemm_nt<0>), grid, blk, 0, stream, (const void*)xq, Wq, (void*)Qh, (const float*)nullptr, B_ * T_, C_);
    hipLaunchKernelGGL((gemm_nt<0>), grid, blk, 0, stream, (const void*)xk, Wk, (void*)Kh, (const float*)nullptr, B_ * T_, C_);
    hipLaunchKernelGGL((gemm_nt<1>), grid, blk, 0, stream, (const void*)xv, Wv, (void*)Vt, (const float*)nullptr, B_ * T_, C_);
    hipLaunchKernelGGL(attn_kernel, dim3(B_ * H_ * (T_ / 128)), blk, 0, stream, Qh, Kh, Vt, Y);
    hipLaunchKernelGGL((gemm_nt<2>), grid, blk, 0, stream, (const void*)Y, Wo, d_out, bo, B_ * T_, C_);
}

// Round 3
// 384.578 us; speedup vs baseline: 1.5801x; 1.2655x over previous
//
#include <hip/hip_runtime.h>
#include <stdint.h>

#define B_ 4
#define T_ 2048
#define C_ 1024
#define H_ 16
#define HD 64

typedef __attribute__((ext_vector_type(8))) short bf16x8;
typedef __attribute__((ext_vector_type(4))) float v4f;
typedef __attribute__((ext_vector_type(4))) uint32_t v4u;

static __device__ __forceinline__ short f2bf(float f) {
    union { float f; uint32_t u; } v; v.f = f;
    uint32_t u = v.u;
    uint32_t r = (u + 0x7fffu + ((u >> 16) & 1u)) >> 16;
    return (short)(r & 0xffffu);
}
static __device__ __forceinline__ short f2bf_trunc(float f) {
    union { float f; uint32_t u; } v; v.f = f;
    return (short)(v.u >> 16);
}
// round-half-up bf16 pack of 2 fp32 -> 1 dword (lo short = x). 3 VALU ops.
static __device__ __forceinline__ uint32_t pack2(float x, float y) {
    uint32_t a = __float_as_uint(x) + 0x8000u;
    uint32_t b = __float_as_uint(y) + 0x8000u;
    return __builtin_amdgcn_perm(b, a, 0x07060302u);  // [a.b2,a.b3,b.b2,b.b3]
}
static __device__ __forceinline__ void gload_lds16(const void* g, void* l) {
    __builtin_amdgcn_global_load_lds(
        (const __attribute__((address_space(1))) void*)g,
        (__attribute__((address_space(3))) void*)l, 16, 0, 0);
}

// Convert 4 weight matrices (1M fp32 each) to bf16. grid (512,4) x 256.
__global__ __launch_bounds__(256) void convw(
    const float* __restrict__ w0, const float* __restrict__ w1,
    const float* __restrict__ w2, const float* __restrict__ w3,
    short* __restrict__ out)
{
    const float* src = (blockIdx.y == 0) ? w0 : (blockIdx.y == 1) ? w1 :
                       (blockIdx.y == 2) ? w2 : w3;
    short* dst = out + (size_t)blockIdx.y * (C_ * C_);
    int id = blockIdx.x * 256 + threadIdx.x;      // chunk of 8 elems
    const float* p = src + (size_t)id * 8;
    v4f a0 = *(const v4f*)p, a1 = *(const v4f*)(p + 4);
    v4u dv;
    dv[0] = pack2(a0[0], a0[1]); dv[1] = pack2(a0[2], a0[3]);
    dv[2] = pack2(a1[0], a1[1]); dv[3] = pack2(a1[2], a1[3]);
    *(v4u*)&dst[(size_t)id * 8] = dv;
}

// Cmat[m][n] = sum_k A[m,k]*Bm[n,k], K=1024, 128x128 tile, 4 waves 2x2,
// LDS unpadded [128][32] (gll-compatible; frag reads at inherent-min aliasing).
// MODE 0: A fp32 x (convert-stage), B bf16 W (gll), out bf16 (b,h,t,d)*oscale
// MODE 1: A bf16 W (gll), B fp32 x (convert-stage), out bf16 (b,h,d,t)
// MODE 2: A bf16 Y (gll), B bf16 W (gll), out fp32 row-major + bias
template <int MODE>
__global__ __launch_bounds__(256) void gemm_nt(
    const void* __restrict__ Aptr, const void* __restrict__ Bptr,
    void* __restrict__ Out, const float* __restrict__ bias, float oscale)
{
    const int K = 1024;
    __shared__ short As[128 * 32];
    __shared__ short Bs[128 * 32];
    const int t = threadIdx.x;
    const int w = t >> 6, l = t & 63, g = l >> 4, c = l & 15;
    const int wm = w & 1, wn = w >> 1;
    const int m0 = blockIdx.x * 128, n0 = blockIdx.y * 128;

    v4f acc[4][4];
#pragma unroll
    for (int i = 0; i < 4; ++i)
#pragma unroll
        for (int j = 0; j < 4; ++j) acc[i][j] = (v4f){0.f, 0.f, 0.f, 0.f};

    for (int k0 = 0; k0 < K; k0 += 32) {
        __syncthreads();
        if (MODE != 0) {  // A bf16 via gll: 8 chunks of 16 rows, 2 per wave
            const short* Ab = (const short*)Aptr;
#pragma unroll
            for (int i = 0; i < 2; ++i) {
                int cb = w * 2 + i;
                const short* gp = Ab + (size_t)(m0 + cb * 16 + (l >> 2)) * K + k0 + (l & 3) * 8;
                gload_lds16(gp, &As[cb * 512]);
            }
        }
        if (MODE != 1) {  // B bf16 via gll
            const short* Bb = (const short*)Bptr;
#pragma unroll
            for (int i = 0; i < 2; ++i) {
                int cb = w * 2 + i;
                const short* gp = Bb + (size_t)(n0 + cb * 16 + (l >> 2)) * K + k0 + (l & 3) * 8;
                gload_lds16(gp, &Bs[cb * 512]);
            }
        }
        if (MODE == 0) {  // A fp32 convert-stage
            const float* Af = (const float*)Aptr;
#pragma unroll
            for (int i = 0; i < 2; ++i) {
                int id = i * 256 + t;
                const float* p = Af + (size_t)(m0 + (id >> 2)) * K + k0 + (id & 3) * 8;
                v4f a0 = *(const v4f*)p, a1 = *(const v4f*)(p + 4);
                v4u dv;
                dv[0] = pack2(a0[0], a0[1]); dv[1] = pack2(a0[2], a0[3]);
                dv[2] = pack2(a1[0], a1[1]); dv[3] = pack2(a1[2], a1[3]);
                *(v4u*)&As[id * 8] = dv;
            }
        }
        if (MODE == 1) {  // B fp32 convert-stage
            const float* Bf = (const float*)Bptr;
#pragma unroll
            for (int i = 0; i < 2; ++i) {
                int id = i * 256 + t;
                const float* p = Bf + (size_t)(n0 + (id >> 2)) * K + k0 + (id & 3) * 8;
                v4f a0 = *(const v4f*)p, a1 = *(const v4f*)(p + 4);
                v4u dv;
                dv[0] = pack2(a0[0], a0[1]); dv[1] = pack2(a0[2], a0[3]);
                dv[2] = pack2(a1[0], a1[1]); dv[3] = pack2(a1[2], a1[3]);
                *(v4u*)&Bs[id * 8] = dv;
            }
        }
        __syncthreads();
        bf16x8 af[4], bfr[4];
#pragma unroll
        for (int i = 0; i < 4; ++i)
            af[i] = *(const bf16x8*)&As[(wm * 64 + i * 16 + c) * 32 + g * 8];
#pragma unroll
        for (int j = 0; j < 4; ++j)
            bfr[j] = *(const bf16x8*)&Bs[(wn * 64 + j * 16 + c) * 32 + g * 8];
#pragma unroll
        for (int i = 0; i < 4; ++i)
#pragma unroll
            for (int j = 0; j < 4; ++j)
                acc[i][j] = __builtin_amdgcn_mfma_f32_16x16x32_bf16(af[i], bfr[j], acc[i][j], 0, 0, 0);
    }
    // C/D: col = lane&15, row = (lane>>4)*4 + reg  [m89/m91]
#pragma unroll
    for (int i = 0; i < 4; ++i)
#pragma unroll
        for (int j = 0; j < 4; ++j)
#pragma unroll
            for (int r = 0; r < 4; ++r) {
                int m = m0 + wm * 64 + i * 16 + g * 4 + r;
                int n = n0 + wn * 64 + j * 16 + c;
                float vv = acc[i][j][r];
                if (MODE == 2) {
                    ((float*)Out)[(size_t)m * C_ + n] = vv + bias[n];
                } else if (MODE == 0) {   // m = token, n = feature
                    int b = m >> 11, tt = m & (T_ - 1);
                    int h = n >> 6, d = n & 63;
                    ((short*)Out)[((size_t)(b * H_ + h) * T_ + tt) * HD + d] = f2bf(vv * oscale);
                } else {                  // MODE 1: m = feature, n = token
                    int b = n >> 11, tt = n & (T_ - 1);
                    int h = m >> 6, d = m & 63;
                    ((short*)Out)[((size_t)(b * H_ + h) * HD + d) * T_ + tt] = f2bf(vv);
                }
            }
}

// Flash attention, causal, no-rescale softmax (scores bounded; Q pre-scaled by
// log2(e)/8 in the Q-GEMM). Q,K: (B,H,T,64) bf16; Vt: (B,H,64,T) bf16;
// Y: (B,T,C) bf16. Block = (b,h,q-tile pair {p,31-p}) -> 33 k-tiles each.
__global__ __launch_bounds__(256) void attn_kernel(
    const short* __restrict__ Q, const short* __restrict__ Kp,
    const short* __restrict__ Vt, short* __restrict__ Y)
{
    __shared__ short Ks[2 * 64 * 32];    // [dim-half][key][32] via gll, 64B rows
    __shared__ short Vs[64 * 72];        // [d][key] pad 72
    __shared__ short Ps[4 * 16 * 72];    // per-wave P: [16 q][64 key] pad 72
    const int t = threadIdx.x;
    const int w = t >> 6, l = t & 63, g = l >> 4, c = l & 15;
    const int p = blockIdx.x & 15;
    const size_t bh = blockIdx.x >> 4;

    bf16x8 ones;
#pragma unroll
    for (int i = 0; i < 8; ++i) ones[i] = (short)0x3F80;  // bf16 1.0

    for (int qi = 0; qi < 2; ++qi) {
        const int qt = qi ? (31 - p) : p;
        const int qbase = qt * 64;

        bf16x8 qf0, qf1;   // pre-scaled Q fragments
        {
            const short* qp = &Q[(bh * T_ + qbase + w * 16 + c) * HD + g * 8];
            qf0 = *(const bf16x8*)qp;
            qf1 = *(const bf16x8*)(qp + 32);
        }

        v4f O[4], accl;
        accl = (v4f){0.f, 0.f, 0.f, 0.f};
#pragma unroll
        for (int d = 0; d < 4; ++d) O[d] = (v4f){0.f, 0.f, 0.f, 0.f};

        for (int kb = 0; kb <= qt; ++kb) {
            const int kbase = kb * 64;
            __syncthreads();
            // K tile via gll: 8 chunks (half,rowblk), 2 per wave
#pragma unroll
            for (int i = 0; i < 2; ++i) {
                int gi = w * 2 + i;
                int hk = gi >> 2, rb = gi & 3;
                const short* gp = &Kp[(bh * T_ + kbase + rb * 16 + (l >> 2)) * HD + hk * 32 + (l & 3) * 8];
                gload_lds16(gp, &Ks[hk * 2048 + rb * 512]);
            }
            // V tile (transposed layout) via VGPR, padded rows
#pragma unroll
            for (int i = 0; i < 2; ++i) {
                int id = i * 256 + t;
                int rr = id >> 3, cc = id & 7;
                *(bf16x8*)&Vs[rr * 72 + cc * 8] =
                    *(const bf16x8*)&Vt[(bh * HD + rr) * T_ + kbase + cc * 8];
            }
            __syncthreads();

            float s2[4][4];
#pragma unroll
            for (int j = 0; j < 4; ++j) {
                bf16x8 kf0 = *(const bf16x8*)&Ks[(j * 16 + c) * 32 + g * 8];
                bf16x8 kf1 = *(const bf16x8*)&Ks[2048 + (j * 16 + c) * 32 + g * 8];
                v4f sa = (v4f){0.f, 0.f, 0.f, 0.f};
                sa = __builtin_amdgcn_mfma_f32_16x16x32_bf16(qf0, kf0, sa, 0, 0, 0);
                sa = __builtin_amdgcn_mfma_f32_16x16x32_bf16(qf1, kf1, sa, 0, 0, 0);
#pragma unroll
                for (int r = 0; r < 4; ++r) s2[j][r] = sa[r];
            }
            if (kb == qt) {  // diagonal tile mask
#pragma unroll
                for (int j = 0; j < 4; ++j) {
                    int key = kbase + j * 16 + c;
#pragma unroll
                    for (int r = 0; r < 4; ++r) {
                        int q = qbase + w * 16 + g * 4 + r;
                        if (key > q) s2[j][r] = -3.0e38f;
                    }
                }
            }
            // p = exp2(s) -> Ps (bf16 trunc); no max subtraction needed
#pragma unroll
            for (int r = 0; r < 4; ++r)
#pragma unroll
                for (int j = 0; j < 4; ++j) {
                    float pp = __builtin_amdgcn_exp2f(s2[j][r]);
                    Ps[w * 1152 + (g * 4 + r) * 72 + j * 16 + c] = f2bf_trunc(pp);
                }
            // PV + row-sum (ones-MFMA)
#pragma unroll
            for (int s = 0; s < 2; ++s) {
                bf16x8 af = *(const bf16x8*)&Ps[w * 1152 + c * 72 + s * 32 + g * 8];
#pragma unroll
                for (int d = 0; d < 4; ++d) {
                    bf16x8 vf = *(const bf16x8*)&Vs[(d * 16 + c) * 72 + s * 32 + g * 8];
                    O[d] = __builtin_amdgcn_mfma_f32_16x16x32_bf16(af, vf, O[d], 0, 0, 0);
                }
                accl = __builtin_amdgcn_mfma_f32_16x16x32_bf16(af, ones, accl, 0, 0, 0);
            }
        }
#pragma unroll
        for (int r = 0; r < 4; ++r) {
            float rl = 1.0f / accl[r];
            size_t rowoff = ((size_t)(bh >> 4) * T_ + qbase + w * 16 + g * 4 + r) * C_ + (bh & 15) * HD;
#pragma unroll
            for (int d = 0; d < 4; ++d)
                Y[rowoff + d * 16 + c] = f2bf(O[d][r] * rl);
        }
    }
}

extern "C" void kernel_launch(void* const* d_in, const int* in_sizes, int n_in,
                              void* d_out, int out_size, void* d_ws, size_t ws_size,
                              hipStream_t stream) {
    const float* xq = (const float*)d_in[0];
    const float* xk = (const float*)d_in[1];
    const float* xv = (const float*)d_in[2];
    const float* Wq = (const float*)d_in[3];
    const float* Wk = (const float*)d_in[4];
    const float* Wv = (const float*)d_in[5];
    const float* Wo = (const float*)d_in[6];
    const float* bo = (const float*)d_in[7];

    const size_t NE = (size_t)B_ * H_ * T_ * HD;   // 8.4M elems
    const size_t WE = (size_t)C_ * C_;             // 1M elems
    short* Qh  = (short*)d_ws;
    short* Kh  = Qh + NE;
    short* Vt  = Kh + NE;
    short* Y   = Vt + NE;
    short* Wbf = Y + NE;                           // 4 x 2MB, total ws ~75MB

    const float qscale = 0.18033688011112042f;     // log2(e)/sqrt(64)
    dim3 blk(256);

    hipLaunchKernelGGL(convw, dim3(512, 4), blk, 0, stream, Wq, Wk, Wv, Wo, Wbf);
    hipLaunchKernelGGL((gemm_nt<0>), dim3(64, 8), blk, 0, stream,
                       (const void*)xq, (const void*)(Wbf + 0 * WE), (void*)Qh, (const float*)nullptr, qscale);
    hipLaunchKernelGGL((gemm_nt<0>), dim3(64, 8), blk, 0, stream,
                       (const void*)xk, (const void*)(Wbf + 1 * WE), (void*)Kh, (const float*)nullptr, 1.0f);
    hipLaunchKernelGGL((gemm_nt<1>), dim3(8, 64), blk, 0, stream,
                       (const void*)(Wbf + 2 * WE), (const void*)xv, (void*)Vt, (const float*)nullptr, 1.0f);
    hipLaunchKernelGGL(attn_kernel, dim3(B_ * H_ * (T_ / 128)), blk, 0, stream, Qh, Kh, Vt, Y);
    hipLaunchKernelGGL((gemm_nt<2>), dim3(64, 8), blk, 0, stream,
                       (const void*)Y, (const void*)(Wbf + 3 * WE), d_out, bo, 1.0f);
}